// Round 9
// baseline (252.054 us; speedup 1.0000x reference)
//
#include <hip/hip_runtime.h>
#include <hip/hip_bf16.h>

#define BB 2
#define NN 2048
#define KVN 2048
#define CC 1024
#define HH 16
#define HD 64

typedef __bf16 bf16;
typedef __attribute__((ext_vector_type(4))) __bf16 bf16x4;
typedef __attribute__((ext_vector_type(8))) __bf16 bf16x8;
typedef __attribute__((ext_vector_type(4))) float f32x4;

__device__ __forceinline__ void gload_lds16(const void* g, void* l) {
  __builtin_amdgcn_global_load_lds(
      (const __attribute__((address_space(1))) void*)g,
      (__attribute__((address_space(3))) void*)l, 16, 0, 0);
}

// ---------------- batched weight transpose: Wt[z][c][r] = (bf16)W_z[r][c]
__global__ __launch_bounds__(256)
void wtrans(const float* __restrict__ qW, const float* __restrict__ kW,
            const float* __restrict__ vW, const float* __restrict__ pW,
            bf16* __restrict__ Wt) {
  __shared__ bf16 t[64][72];
  const float* in = (blockIdx.z == 0) ? qW : (blockIdx.z == 1) ? kW
                    : (blockIdx.z == 2) ? vW : pW;
  bf16* out = Wt + (size_t)blockIdx.z * CC * CC;
  int r0 = blockIdx.y * 64, c0 = blockIdx.x * 64;
  int tid = threadIdx.x;
  int lr = tid >> 3, lc = (tid & 7) * 8;
  for (int p = 0; p < 2; ++p) {
    int rr = lr + p * 32;
    const float* src = &in[(size_t)(r0 + rr) * CC + c0 + lc];
    float4 a = *(const float4*)src;
    float4 b = *(const float4*)(src + 4);
    t[lc + 0][rr] = (bf16)a.x; t[lc + 1][rr] = (bf16)a.y;
    t[lc + 2][rr] = (bf16)a.z; t[lc + 3][rr] = (bf16)a.w;
    t[lc + 4][rr] = (bf16)b.x; t[lc + 5][rr] = (bf16)b.y;
    t[lc + 6][rr] = (bf16)b.z; t[lc + 7][rr] = (bf16)b.w;
  }
  __syncthreads();
  for (int p = 0; p < 2; ++p) {
    int rr = lr + p * 32;
    *(bf16x8*)&out[(size_t)(c0 + rr) * CC + r0 + lc] = *(const bf16x8*)&t[rr][lc];
  }
}

// ---------------- merged QKV GEMM (round-7 proven): 128x128, BK=64, zero-conflict
// 8-slot swizzle, A cvt'd fp32->bf16 at stage time, RoPE fused (z<2).
__global__ __launch_bounds__(256, 3)
void gemm_qkv(const float* __restrict__ qin, const float* __restrict__ kin,
              const float* __restrict__ vin, const bf16* __restrict__ Wt,
              const float* __restrict__ pos, bf16* __restrict__ Qp,
              bf16* __restrict__ Kp, bf16* __restrict__ Vp) {
  __shared__ bf16 As[128 * 64];   // chunks of 8: L = r*8 + (c^(r&7))
  __shared__ bf16 Bs[128 * 64];
  const int bid = blockIdx.x;
  const int u = bid & 7, s = bid >> 3;       // s in [0,96)
  const int nblk = s >> 2;                   // 0..23
  const int m0 = (u * 4 + (s & 3)) * 128;
  const int z = nblk >> 3;
  const int n0 = (nblk & 7) * 128;
  const float* A = (z == 0) ? qin : (z == 1) ? kin : vin;
  const bf16* Bt = Wt + (size_t)z * CC * CC;
  bf16* Out = (z == 0) ? Qp : (z == 1) ? Kp : Vp;
  const int tid = threadIdx.x;
  const int wave = tid >> 6, lane = tid & 63;
  const int quad = lane >> 4, l15 = lane & 15;
  const int waveM = (wave >> 1) * 64, waveN = (wave & 1) * 64;
  f32x4 acc[4][4] = {};

  for (int k0 = 0; k0 < CC; k0 += 64) {
#pragma unroll
    for (int p = 0; p < 4; ++p) {   // B: async direct-to-LDS
      int ch = p * 256 + tid;
      int r = ch >> 3, c = (ch & 7) ^ (r & 7);
      gload_lds16(Bt + (size_t)(n0 + r) * CC + k0 + c * 8, &Bs[ch * 8]);
    }
#pragma unroll
    for (int p = 0; p < 4; ++p) {   // A: fp32 -> bf16 through regs, b128 write
      int ch = p * 256 + tid;
      int r = ch >> 3, c = (ch & 7) ^ (r & 7);
      const float* src = A + (size_t)(m0 + r) * CC + k0 + c * 8;
      float4 a0 = *(const float4*)src;
      float4 a1 = *(const float4*)(src + 4);
      bf16x8 t;
      t[0] = (bf16)a0.x; t[1] = (bf16)a0.y; t[2] = (bf16)a0.z; t[3] = (bf16)a0.w;
      t[4] = (bf16)a1.x; t[5] = (bf16)a1.y; t[6] = (bf16)a1.z; t[7] = (bf16)a1.w;
      *(bf16x8*)&As[ch * 8] = t;
    }
    __syncthreads();
    bf16x8 af[4][2], bfr[4][2];
#pragma unroll
    for (int i = 0; i < 4; ++i) {
      int rA = waveM + i * 16 + l15;
      af[i][0] = *(const bf16x8*)&As[(rA * 8 + (quad ^ (rA & 7))) * 8];
      af[i][1] = *(const bf16x8*)&As[(rA * 8 + ((quad + 4) ^ (rA & 7))) * 8];
      int rB = waveN + i * 16 + l15;
      bfr[i][0] = *(const bf16x8*)&Bs[(rB * 8 + (quad ^ (rB & 7))) * 8];
      bfr[i][1] = *(const bf16x8*)&Bs[(rB * 8 + ((quad + 4) ^ (rB & 7))) * 8];
    }
#pragma unroll
    for (int mi = 0; mi < 4; ++mi)
#pragma unroll
      for (int ni = 0; ni < 4; ++ni) {
        acc[mi][ni] = __builtin_amdgcn_mfma_f32_16x16x32_bf16(
            af[mi][0], bfr[ni][0], acc[mi][ni], 0, 0, 0);
        acc[mi][ni] = __builtin_amdgcn_mfma_f32_16x16x32_bf16(
            af[mi][1], bfr[ni][1], acc[mi][ni], 0, 0, 0);
      }
    __syncthreads();
  }
  const float scale = (z == 0) ? 0.125f : 1.0f;
#pragma unroll
  for (int mi = 0; mi < 4; ++mi) {
#pragma unroll
    for (int r = 0; r < 4; ++r) {
      int m = m0 + waveM + mi * 16 + quad * 4 + r;
      int l = m & (NN - 1);
      if (z == 2) {
#pragma unroll
        for (int ni = 0; ni < 4; ++ni)
          Out[(size_t)m * CC + n0 + waveN + ni * 16 + l15] = (bf16)acc[mi][ni][r];
      } else {
#pragma unroll
        for (int ni = 0; ni < 2; ++ni) {
          int col = n0 + waveN + ni * 16 + l15;
          int d = ni * 16 + l15;                 // head-local, in [0,32)
          float x1 = acc[mi][ni][r], x2 = acc[mi][ni + 2][r];
          float s1, c1, s2f, c2f;
          __sincosf(pos[l * HD + d], &s1, &c1);
          __sincosf(pos[l * HD + d + 32], &s2f, &c2f);
          Out[(size_t)m * CC + col]      = (bf16)((x1 * c1 - x2 * s1) * scale);
          Out[(size_t)m * CC + col + 32] = (bf16)((x2 * c2f + x1 * s2f) * scale);
        }
      }
    }
  }
}

// ---------------- V pack: V^T in A-frag order, pre-masked, + mask row (d=64)
__global__ __launch_bounds__(256)
void vpack_kernel(const bf16* __restrict__ Vp, const int* __restrict__ mask,
                  bf16* __restrict__ VpA, bf16* __restrict__ VpB) {
  __shared__ bf16 t[64][80];
  int tix = blockIdx.x, h = blockIdx.y, b = blockIdx.z;
  int j0 = tix * 64, bh = b * HH + h;
  const int* maskb = mask + b * KVN;
  int tid = threadIdx.x;
  int lr = tid >> 3, lc = (tid & 7) * 8;
  for (int p = 0; p < 2; ++p) {
    int j = lr + p * 32;
    int mv = maskb[j0 + j];
    bf16x8 v = *(const bf16x8*)&Vp[(size_t)(b * KVN + j0 + j) * CC + h * HD + lc];
#pragma unroll
    for (int uu = 0; uu < 8; ++uu) t[lc + uu][j] = mv ? v[uu] : (bf16)0.f;
  }
  __syncthreads();
  for (int p = 0; p < 3; ++p) {
    int sp = p * 256 + tid;
    if (sp < 640) {
      int fs = sp >> 6, lane = sp & 63, quad = (sp >> 4) & 3, l15 = sp & 15;
      int ni = fs >> 1, hf = fs & 1;
      bf16x8 v;
      if (ni < 4) {
        v = *(const bf16x8*)&t[ni * 16 + l15][hf * 32 + quad * 8];
      } else {
#pragma unroll
        for (int jj = 0; jj < 8; ++jj)
          v[jj] = (l15 == 0) ? (bf16)(float)maskb[j0 + hf * 32 + quad * 8 + jj]
                             : (bf16)0.f;
      }
      bf16* dst = (fs < 6) ? (VpA + (size_t)fs * (1 << 19))
                           : (VpB + (size_t)(fs - 6) * (1 << 19));
      *(bf16x8*)&dst[((size_t)(bh * 32 + tix)) * 512 + lane * 8] = v;
    }
  }
}

// ---------------- attention v4: block = 2 waves x 64 queries, full key range.
// K/V tile (18 KB) dbuf-staged per block, shared by both waves; K from row-major
// Kp (swizzled slots), V from packed frag buffers; mask-row MFMA gives lsum.
__global__ __launch_bounds__(128, 2)
void attn4(const bf16* __restrict__ Qp, const bf16* __restrict__ Kp,
           const bf16* __restrict__ VpA, const bf16* __restrict__ VpB,
           bf16* __restrict__ X) {
  __shared__ bf16 Ks[2][64 * 64];    // 8 KB per buf, slot L = r*8 + (c^(r&7))
  __shared__ bf16 Vs[2][640 * 8];    // 10 KB per buf, frag-linear
  __shared__ bf16 Ps[2][1024];       // per-wave P scratch (2 KB)
  const int tid = threadIdx.x, wave = tid >> 6, lane = tid & 63;
  const int quad = lane >> 4, l15 = lane & 15;
  const int bid = blockIdx.x;
  const int u = bid & 7, s = bid >> 3;          // s in [0,64)
  const int bh = u * 4 + (s & 3), qp = s >> 2;  // qp in [0,16)
  const int b = bh >> 4, h = bh & 15;
  const int q0 = qp * 128 + wave * 64;
  const int sw = 2 * (l15 & 7);
  bf16* P = Ps[wave];

  bf16x8 qa[4][2];
#pragma unroll
  for (int g = 0; g < 4; ++g) {
    const bf16* qrow = Qp + ((size_t)(b * NN) + q0 + g * 16 + l15) * CC + h * HD;
    qa[g][0] = *(const bf16x8*)&qrow[quad * 8];
    qa[g][1] = *(const bf16x8*)&qrow[32 + quad * 8];
  }

  f32x4 Oacc[4][5] = {};

#define STAGE(t, bufi)                                                        \
  {                                                                           \
    _Pragma("unroll") for (int p = 0; p < 9; ++p) {                           \
      int ch = p * 128 + tid;                                                 \
      if (ch < 512) {                                                         \
        int r = ch >> 3, c = (ch & 7) ^ (r & 7);                              \
        gload_lds16(Kp + ((size_t)(b * KVN + (t) * 64 + r)) * CC + h * HD + c * 8, \
                    &Ks[bufi][ch * 8]);                                       \
      } else {                                                                \
        int idx = ch - 512;                                                   \
        int fs = idx >> 6, ln = idx & 63;                                     \
        const bf16* vbs = (fs < 6) ? (VpA + (size_t)fs * (1 << 19))           \
                                   : (VpB + (size_t)(fs - 6) * (1 << 19));    \
        gload_lds16(vbs + ((size_t)(bh * 32 + (t))) * 512 + ln * 8,           \
                    &Vs[bufi][idx * 8]);                                      \
      }                                                                       \
    }                                                                         \
  }

  STAGE(0, 0);
  __syncthreads();

  for (int t = 0; t < 32; ++t) {
    const int buf = t & 1;
    bf16x8 kb[4][2], vb[10];
#pragma unroll
    for (int ni = 0; ni < 4; ++ni) {
      int rk = ni * 16 + l15;
#pragma unroll
      for (int hf = 0; hf < 2; ++hf)
        kb[ni][hf] = *(const bf16x8*)&Ks[buf][(rk * 8 + ((hf * 4 + quad) ^ (rk & 7))) * 8];
    }
#pragma unroll
    for (int fs = 0; fs < 10; ++fs)
      vb[fs] = *(const bf16x8*)&Vs[buf][(fs * 64 + lane) * 8];
    if (t + 1 < 32) STAGE(t + 1, buf ^ 1);
#pragma unroll
    for (int g = 0; g < 4; ++g) {
      f32x4 sg[4];
#pragma unroll
      for (int ni = 0; ni < 4; ++ni) {
        f32x4 zz = {};
        zz = __builtin_amdgcn_mfma_f32_16x16x32_bf16(kb[ni][0], qa[g][0], zz, 0, 0, 0);
        zz = __builtin_amdgcn_mfma_f32_16x16x32_bf16(kb[ni][1], qa[g][1], zz, 0, 0, 0);
        sg[ni] = zz;
      }
#pragma unroll
      for (int ni = 0; ni < 4; ++ni) {
        bf16x4 pk;
#pragma unroll
        for (int r = 0; r < 4; ++r) pk[r] = (bf16)__expf(sg[ni][r] - 4.0f);
        *(bf16x4*)&P[(l15 * 16 + ((ni * 4 + quad) ^ sw)) * 4] = pk;
      }
      bf16x8 pf0 = *(const bf16x8*)&P[(l15 * 16 + ((quad * 2) ^ sw)) * 4];
      bf16x8 pf1 = *(const bf16x8*)&P[(l15 * 16 + ((8 + quad * 2) ^ sw)) * 4];
#pragma unroll
      for (int ni = 0; ni < 5; ++ni) {
        Oacc[g][ni] = __builtin_amdgcn_mfma_f32_16x16x32_bf16(vb[ni * 2], pf0, Oacc[g][ni], 0, 0, 0);
        Oacc[g][ni] = __builtin_amdgcn_mfma_f32_16x16x32_bf16(vb[ni * 2 + 1], pf1, Oacc[g][ni], 0, 0, 0);
      }
    }
    __syncthreads();   // prefetch drained before next iter reads buf^1
  }
#undef STAGE
#pragma unroll
  for (int g = 0; g < 4; ++g) {
    float ls = __shfl(Oacc[g][4][0], l15, 64);
    float rn = 1.0f / ls;
#pragma unroll
    for (int ni = 0; ni < 4; ++ni) {
      bf16x4 ov;
#pragma unroll
      for (int r = 0; r < 4; ++r) ov[r] = (bf16)(Oacc[g][ni][r] * rn);
      *(bf16x4*)&X[((size_t)(b * NN) + q0 + g * 16 + l15) * CC
                   + h * HD + ni * 16 + quad * 4] = ov;
    }
  }
}

// ---------------- projection GEMM: 64x128 tile, BK=64, 8-slot swizzle, grid 512
__global__ __launch_bounds__(256, 4)
void gemm_proj(const bf16* __restrict__ A, const bf16* __restrict__ Bt,
               float* __restrict__ Out) {
  __shared__ bf16 As[64 * 64];
  __shared__ bf16 Bs[128 * 64];
  const int bid = blockIdx.x;
  const int u = bid & 7, s = bid >> 3;        // s in [0,64)
  const int m0 = (u * 8 + (s >> 3)) * 64;
  const int n0 = (s & 7) * 128;
  const int tid = threadIdx.x;
  const int wave = tid >> 6, lane = tid & 63;
  const int quad = lane >> 4, l15 = lane & 15;
  const int waveM = (wave >> 1) * 32, waveN = (wave & 1) * 64;
  f32x4 acc[2][4] = {};

  for (int k0 = 0; k0 < CC; k0 += 64) {
#pragma unroll
    for (int p = 0; p < 2; ++p) {
      int ch = p * 256 + tid;
      int r = ch >> 3, c = (ch & 7) ^ (r & 7);
      gload_lds16(A + (size_t)(m0 + r) * CC + k0 + c * 8, &As[ch * 8]);
    }
#pragma unroll
    for (int p = 0; p < 4; ++p) {
      int ch = p * 256 + tid;
      int r = ch >> 3, c = (ch & 7) ^ (r & 7);
      gload_lds16(Bt + (size_t)(n0 + r) * CC + k0 + c * 8, &Bs[ch * 8]);
    }
    __syncthreads();
    bf16x8 af[2][2], bfr[4][2];
#pragma unroll
    for (int i = 0; i < 2; ++i) {
      int rA = waveM + i * 16 + l15;
      af[i][0] = *(const bf16x8*)&As[(rA * 8 + (quad ^ (rA & 7))) * 8];
      af[i][1] = *(const bf16x8*)&As[(rA * 8 + ((quad + 4) ^ (rA & 7))) * 8];
    }
#pragma unroll
    for (int i = 0; i < 4; ++i) {
      int rB = waveN + i * 16 + l15;
      bfr[i][0] = *(const bf16x8*)&Bs[(rB * 8 + (quad ^ (rB & 7))) * 8];
      bfr[i][1] = *(const bf16x8*)&Bs[(rB * 8 + ((quad + 4) ^ (rB & 7))) * 8];
    }
#pragma unroll
    for (int mi = 0; mi < 2; ++mi)
#pragma unroll
      for (int ni = 0; ni < 4; ++ni) {
        acc[mi][ni] = __builtin_amdgcn_mfma_f32_16x16x32_bf16(
            af[mi][0], bfr[ni][0], acc[mi][ni], 0, 0, 0);
        acc[mi][ni] = __builtin_amdgcn_mfma_f32_16x16x32_bf16(
            af[mi][1], bfr[ni][1], acc[mi][ni], 0, 0, 0);
      }
    __syncthreads();
  }
#pragma unroll
  for (int mi = 0; mi < 2; ++mi)
#pragma unroll
    for (int ni = 0; ni < 4; ++ni)
#pragma unroll
      for (int r = 0; r < 4; ++r) {
        int row = m0 + waveM + mi * 16 + quad * 4 + r;
        int col = n0 + waveN + ni * 16 + l15;
        Out[(size_t)row * CC + col] = acc[mi][ni][r];
      }
}

extern "C" void kernel_launch(void* const* d_in, const int* in_sizes, int n_in,
                              void* d_out, int out_size, void* d_ws, size_t ws_size,
                              hipStream_t stream) {
  const float* q    = (const float*)d_in[0];
  const float* k    = (const float*)d_in[1];
  const float* v    = (const float*)d_in[2];
  const int*   mask = (const int*)d_in[3];
  const float* pos  = (const float*)d_in[4];
  const float* qW   = (const float*)d_in[5];
  const float* kW   = (const float*)d_in[6];
  const float* vW   = (const float*)d_in[7];
  const float* pW   = (const float*)d_in[8];
  float* out = (float*)d_out;

  char* w = (char*)d_ws;
  const size_t MB = 1024 * 1024;
  // ws <= 44 MB, verified timeline:
  //  wtrans:    W Wt[0,8)
  //  gemm_qkv:  R d_in,Wt      W Qp[8,16) Kp[16,24) Vp[24,32)
  //  vpack:     R Vp[24,32)    W VpA[0,6) (over dead qWt/kWt/vWt; pWt[6,8) kept)
  //                              VpB[32,36)
  //  attn4:     R Qp,Kp,VpA,VpB  W X[36,44)
  //  gemm_proj: R X,pWt[6,8)   W d_out
  bf16* Wt  = (bf16*)(w);
  bf16* Qp  = (bf16*)(w + 8 * MB);
  bf16* Kp  = (bf16*)(w + 16 * MB);
  bf16* Vp  = (bf16*)(w + 24 * MB);
  bf16* VpA = (bf16*)(w);
  bf16* VpB = (bf16*)(w + 32 * MB);
  bf16* X   = (bf16*)(w + 36 * MB);

  wtrans<<<dim3(16, 16, 4), 256, 0, stream>>>(qW, kW, vW, pW, Wt);
  gemm_qkv<<<dim3(768), 256, 0, stream>>>(q, k, v, Wt, pos, Qp, Kp, Vp);
  vpack_kernel<<<dim3(KVN / 64, HH, BB), 256, 0, stream>>>(Vp, mask, VpA, VpB);
  attn4<<<dim3(512), 128, 0, stream>>>(Qp, Kp, VpA, VpB, X);
  gemm_proj<<<dim3(512), 256, 0, stream>>>(X, Wt + 3 * (size_t)CC * CC, out);
}

// Round 10
// 228.523 us; speedup vs baseline: 1.1030x; 1.1030x over previous
//
#include <hip/hip_runtime.h>
#include <hip/hip_bf16.h>

#define BB 2
#define NN 2048
#define KVN 2048
#define CC 1024
#define HH 16
#define HD 64

typedef __bf16 bf16;
typedef __attribute__((ext_vector_type(4))) __bf16 bf16x4;
typedef __attribute__((ext_vector_type(8))) __bf16 bf16x8;
typedef __attribute__((ext_vector_type(4))) float f32x4;

__device__ __forceinline__ void gload_lds16(const void* g, void* l) {
  __builtin_amdgcn_global_load_lds(
      (const __attribute__((address_space(1))) void*)g,
      (__attribute__((address_space(3))) void*)l, 16, 0, 0);
}

// ---------------- batched weight transpose: Wt[z][c][r] = (bf16)W_z[r][c]
__global__ __launch_bounds__(256)
void wtrans(const float* __restrict__ qW, const float* __restrict__ kW,
            const float* __restrict__ vW, const float* __restrict__ pW,
            bf16* __restrict__ Wt) {
  __shared__ bf16 t[64][72];
  const float* in = (blockIdx.z == 0) ? qW : (blockIdx.z == 1) ? kW
                    : (blockIdx.z == 2) ? vW : pW;
  bf16* out = Wt + (size_t)blockIdx.z * CC * CC;
  int r0 = blockIdx.y * 64, c0 = blockIdx.x * 64;
  int tid = threadIdx.x;
  int lr = tid >> 3, lc = (tid & 7) * 8;
  for (int p = 0; p < 2; ++p) {
    int rr = lr + p * 32;
    const float* src = &in[(size_t)(r0 + rr) * CC + c0 + lc];
    float4 a = *(const float4*)src;
    float4 b = *(const float4*)(src + 4);
    t[lc + 0][rr] = (bf16)a.x; t[lc + 1][rr] = (bf16)a.y;
    t[lc + 2][rr] = (bf16)a.z; t[lc + 3][rr] = (bf16)a.w;
    t[lc + 4][rr] = (bf16)b.x; t[lc + 5][rr] = (bf16)b.y;
    t[lc + 6][rr] = (bf16)b.z; t[lc + 7][rr] = (bf16)b.w;
  }
  __syncthreads();
  for (int p = 0; p < 2; ++p) {
    int rr = lr + p * 32;
    *(bf16x8*)&out[(size_t)(c0 + rr) * CC + r0 + lc] = *(const bf16x8*)&t[rr][lc];
  }
}

// ---------------- merged QKV GEMM: 128x128, BK=64, zero-conflict 8-slot swizzle,
// A fp32 loads SW-pipelined (regs for k0+64 loaded under MFMA), RoPE fused (z<2).
__global__ __launch_bounds__(256, 3)
void gemm_qkv(const float* __restrict__ qin, const float* __restrict__ kin,
              const float* __restrict__ vin, const bf16* __restrict__ Wt,
              const float* __restrict__ pos, bf16* __restrict__ Qp,
              bf16* __restrict__ Kp, bf16* __restrict__ Vp) {
  __shared__ bf16 As[128 * 64];   // chunks of 8: L = r*8 + (c^(r&7))
  __shared__ bf16 Bs[128 * 64];
  const int bid = blockIdx.x;
  const int u = bid & 7, s = bid >> 3;       // s in [0,96)
  const int nblk = s >> 2;                   // 0..23
  const int m0 = (u * 4 + (s & 3)) * 128;
  const int z = nblk >> 3;
  const int n0 = (nblk & 7) * 128;
  const float* A = (z == 0) ? qin : (z == 1) ? kin : vin;
  const bf16* Bt = Wt + (size_t)z * CC * CC;
  bf16* Out = (z == 0) ? Qp : (z == 1) ? Kp : Vp;
  const int tid = threadIdx.x;
  const int wave = tid >> 6, lane = tid & 63;
  const int quad = lane >> 4, l15 = lane & 15;
  const int waveM = (wave >> 1) * 64, waveN = (wave & 1) * 64;
  f32x4 acc[4][4] = {};

  // per-thread A chunk coords (fixed across k0)
  int chR[4], chC[4];
#pragma unroll
  for (int p = 0; p < 4; ++p) {
    int ch = p * 256 + tid;
    chR[p] = ch >> 3;
    chC[p] = ((ch & 7) ^ (chR[p] & 7)) * 8;
  }
  // prologue: A regs for k0 = 0
  float4 a0[4], a1[4];
#pragma unroll
  for (int p = 0; p < 4; ++p) {
    const float* src = A + (size_t)(m0 + chR[p]) * CC + chC[p];
    a0[p] = *(const float4*)src;
    a1[p] = *(const float4*)(src + 4);
  }

  for (int k0 = 0; k0 < CC; k0 += 64) {
#pragma unroll
    for (int p = 0; p < 4; ++p) {   // B: async direct-to-LDS
      int ch = p * 256 + tid;
      int r = ch >> 3, c = (ch & 7) ^ (r & 7);
      gload_lds16(Bt + (size_t)(n0 + r) * CC + k0 + c * 8, &Bs[ch * 8]);
    }
#pragma unroll
    for (int p = 0; p < 4; ++p) {   // A: cvt regs -> b128 LDS write
      int ch = p * 256 + tid;
      bf16x8 t;
      t[0] = (bf16)a0[p].x; t[1] = (bf16)a0[p].y;
      t[2] = (bf16)a0[p].z; t[3] = (bf16)a0[p].w;
      t[4] = (bf16)a1[p].x; t[5] = (bf16)a1[p].y;
      t[6] = (bf16)a1[p].z; t[7] = (bf16)a1[p].w;
      *(bf16x8*)&As[ch * 8] = t;
    }
    __syncthreads();
    // prefetch next-k0 A into regs: overlaps frag reads + MFMA below
    if (k0 + 64 < CC) {
#pragma unroll
      for (int p = 0; p < 4; ++p) {
        const float* src = A + (size_t)(m0 + chR[p]) * CC + (k0 + 64) + chC[p];
        a0[p] = *(const float4*)src;
        a1[p] = *(const float4*)(src + 4);
      }
    }
    bf16x8 af[4][2], bfr[4][2];
#pragma unroll
    for (int i = 0; i < 4; ++i) {
      int rA = waveM + i * 16 + l15;
      af[i][0] = *(const bf16x8*)&As[(rA * 8 + (quad ^ (rA & 7))) * 8];
      af[i][1] = *(const bf16x8*)&As[(rA * 8 + ((quad + 4) ^ (rA & 7))) * 8];
      int rB = waveN + i * 16 + l15;
      bfr[i][0] = *(const bf16x8*)&Bs[(rB * 8 + (quad ^ (rB & 7))) * 8];
      bfr[i][1] = *(const bf16x8*)&Bs[(rB * 8 + ((quad + 4) ^ (rB & 7))) * 8];
    }
#pragma unroll
    for (int mi = 0; mi < 4; ++mi)
#pragma unroll
      for (int ni = 0; ni < 4; ++ni) {
        acc[mi][ni] = __builtin_amdgcn_mfma_f32_16x16x32_bf16(
            af[mi][0], bfr[ni][0], acc[mi][ni], 0, 0, 0);
        acc[mi][ni] = __builtin_amdgcn_mfma_f32_16x16x32_bf16(
            af[mi][1], bfr[ni][1], acc[mi][ni], 0, 0, 0);
      }
    __syncthreads();
  }
  const float scale = (z == 0) ? 0.125f : 1.0f;
#pragma unroll
  for (int mi = 0; mi < 4; ++mi) {
#pragma unroll
    for (int r = 0; r < 4; ++r) {
      int m = m0 + waveM + mi * 16 + quad * 4 + r;
      int l = m & (NN - 1);
      if (z == 2) {
#pragma unroll
        for (int ni = 0; ni < 4; ++ni)
          Out[(size_t)m * CC + n0 + waveN + ni * 16 + l15] = (bf16)acc[mi][ni][r];
      } else {
#pragma unroll
        for (int ni = 0; ni < 2; ++ni) {
          int col = n0 + waveN + ni * 16 + l15;
          int d = ni * 16 + l15;                 // head-local, in [0,32)
          float x1 = acc[mi][ni][r], x2 = acc[mi][ni + 2][r];
          float s1, c1, s2f, c2f;
          __sincosf(pos[l * HD + d], &s1, &c1);
          __sincosf(pos[l * HD + d + 32], &s2f, &c2f);
          Out[(size_t)m * CC + col]      = (bf16)((x1 * c1 - x2 * s1) * scale);
          Out[(size_t)m * CC + col + 32] = (bf16)((x2 * c2f + x1 * s2f) * scale);
        }
      }
    }
  }
}

// ---------------- K pack: MFMA-A-frag order (round-7 proven)
__global__ __launch_bounds__(256)
void kpack_kernel(const bf16* __restrict__ Kp, bf16* __restrict__ Kpack) {
  int tix = blockIdx.x, h = blockIdx.y, b = blockIdx.z;
  int bh = b * HH + h;
#pragma unroll
  for (int p = 0; p < 2; ++p) {
    int sp = p * 256 + threadIdx.x;
    int fs = sp >> 6, lane = sp & 63, quad = (sp >> 4) & 3, l15 = sp & 15;
    int ni = fs >> 1, hf = fs & 1;
    bf16x8 v = *(const bf16x8*)&Kp[((size_t)(b * KVN + tix * 64 + ni * 16 + l15)) * CC
                                   + h * HD + hf * 32 + quad * 8];
    *(bf16x8*)&Kpack[(((size_t)(bh * 32 + tix)) * 8 + fs) * 512 + lane * 8] = v;
  }
}

// ---------------- V pack: V^T in A-frag order, pre-masked, + mask row (d=64)
__global__ __launch_bounds__(256)
void vpack_kernel(const bf16* __restrict__ Vp, const int* __restrict__ mask,
                  bf16* __restrict__ VpA, bf16* __restrict__ VpB) {
  __shared__ bf16 t[64][80];
  int tix = blockIdx.x, h = blockIdx.y, b = blockIdx.z;
  int j0 = tix * 64, bh = b * HH + h;
  const int* maskb = mask + b * KVN;
  int tid = threadIdx.x;
  int lr = tid >> 3, lc = (tid & 7) * 8;
  for (int p = 0; p < 2; ++p) {
    int j = lr + p * 32;
    int mv = maskb[j0 + j];
    bf16x8 v = *(const bf16x8*)&Vp[(size_t)(b * KVN + j0 + j) * CC + h * HD + lc];
#pragma unroll
    for (int uu = 0; uu < 8; ++uu) t[lc + uu][j] = mv ? v[uu] : (bf16)0.f;
  }
  __syncthreads();
  for (int p = 0; p < 3; ++p) {
    int sp = p * 256 + tid;
    if (sp < 640) {
      int fs = sp >> 6, lane = sp & 63, quad = (sp >> 4) & 3, l15 = sp & 15;
      int ni = fs >> 1, hf = fs & 1;
      bf16x8 v;
      if (ni < 4) {
        v = *(const bf16x8*)&t[ni * 16 + l15][hf * 32 + quad * 8];
      } else {
#pragma unroll
        for (int jj = 0; jj < 8; ++jj)
          v[jj] = (l15 == 0) ? (bf16)(float)maskb[j0 + hf * 32 + quad * 8 + jj]
                             : (bf16)0.f;
      }
      bf16* dst = (fs < 6) ? (VpA + (size_t)fs * (1 << 19))
                           : (VpB + (size_t)(fs - 6) * (1 << 19));
      *(bf16x8*)&dst[((size_t)(bh * 32 + tix)) * 512 + lane * 8] = v;
    }
  }
}

// ---------------- attention v3 (round-7 proven): per-wave, frag-streamed from L2,
// no barriers in loop; S^T = mfma(K,Q); mask-row MFMA gives lsum.
__global__ __launch_bounds__(256, 2)
void attn3(const bf16* __restrict__ Qp, const bf16* __restrict__ Kpack,
           const bf16* __restrict__ VpA, const bf16* __restrict__ VpB,
           bf16* __restrict__ X) {
  __shared__ char smem[49152];      // [0,8K): per-wave P; [8K,48K): merge buffer
  const int tid = threadIdx.x, wave = tid >> 6, lane = tid & 63;
  const int quad = lane >> 4, l15 = lane & 15;
  const int bid = blockIdx.x;
  const int u = bid & 7, s = bid >> 3;
  const int bh = u * 4 + (s & 3), qp = s >> 2;
  const int b = bh >> 4, h = bh & 15;
  const int qc = qp * 2 + (wave >> 1), kh = wave & 1;
  const int q0 = qc * 64;
  const int sw = 2 * (l15 & 7);

  bf16* P = (bf16*)(smem + wave * 2048);
  float* mrg = (float*)(smem + 8192);

  bf16x8 qa[4][2];
#pragma unroll
  for (int g = 0; g < 4; ++g) {
    const bf16* qrow = Qp + ((size_t)(b * NN) + q0 + g * 16 + l15) * CC + h * HD;
    qa[g][0] = *(const bf16x8*)&qrow[quad * 8];
    qa[g][1] = *(const bf16x8*)&qrow[32 + quad * 8];
  }

  f32x4 Oacc[4][5] = {};
  const bf16* kbase = Kpack + (size_t)bh * 32 * 8 * 512;

  for (int it = 0; it < 16; ++it) {
    int t = kh * 16 + it;
    bf16x8 kb[8], vb[10];
#pragma unroll
    for (int fs = 0; fs < 8; ++fs)
      kb[fs] = *(const bf16x8*)&kbase[((size_t)t * 8 + fs) * 512 + lane * 8];
#pragma unroll
    for (int fs = 0; fs < 10; ++fs) {
      const bf16* vbs = (fs < 6) ? (VpA + (size_t)fs * (1 << 19))
                                 : (VpB + (size_t)(fs - 6) * (1 << 19));
      vb[fs] = *(const bf16x8*)&vbs[((size_t)(bh * 32 + t)) * 512 + lane * 8];
    }
#pragma unroll
    for (int g = 0; g < 4; ++g) {
      f32x4 sg[4];
#pragma unroll
      for (int ni = 0; ni < 4; ++ni) {
        f32x4 zz = {};
        zz = __builtin_amdgcn_mfma_f32_16x16x32_bf16(kb[ni * 2], qa[g][0], zz, 0, 0, 0);
        zz = __builtin_amdgcn_mfma_f32_16x16x32_bf16(kb[ni * 2 + 1], qa[g][1], zz, 0, 0, 0);
        sg[ni] = zz;
      }
#pragma unroll
      for (int ni = 0; ni < 4; ++ni) {
        bf16x4 pk;
#pragma unroll
        for (int r = 0; r < 4; ++r) pk[r] = (bf16)__expf(sg[ni][r] - 4.0f);
        *(bf16x4*)&P[(l15 * 16 + ((ni * 4 + quad) ^ sw)) * 4] = pk;
      }
      bf16x8 pf0 = *(const bf16x8*)&P[(l15 * 16 + ((quad * 2) ^ sw)) * 4];
      bf16x8 pf1 = *(const bf16x8*)&P[(l15 * 16 + ((8 + quad * 2) ^ sw)) * 4];
#pragma unroll
      for (int ni = 0; ni < 5; ++ni) {
        Oacc[g][ni] = __builtin_amdgcn_mfma_f32_16x16x32_bf16(vb[ni * 2], pf0, Oacc[g][ni], 0, 0, 0);
        Oacc[g][ni] = __builtin_amdgcn_mfma_f32_16x16x32_bf16(vb[ni * 2 + 1], pf1, Oacc[g][ni], 0, 0, 0);
      }
    }
  }
  if (kh == 1) {
    float* dst = mrg + (wave >> 1) * 5120 + lane * 4;
#pragma unroll
    for (int g = 0; g < 4; ++g)
#pragma unroll
      for (int ni = 0; ni < 5; ++ni)
        *(f32x4*)&dst[(g * 5 + ni) * 256] = Oacc[g][ni];
  }
  __syncthreads();
  if (kh == 0) {
    float* src = mrg + (wave >> 1) * 5120 + lane * 4;
#pragma unroll
    for (int g = 0; g < 4; ++g) {
#pragma unroll
      for (int ni = 0; ni < 5; ++ni) {
        f32x4 o = *(const f32x4*)&src[(g * 5 + ni) * 256];
#pragma unroll
        for (int r = 0; r < 4; ++r) Oacc[g][ni][r] += o[r];
      }
      float ls = __shfl(Oacc[g][4][0], l15, 64);
      float rn = 1.0f / ls;
#pragma unroll
      for (int ni = 0; ni < 4; ++ni) {
        bf16x4 ov;
#pragma unroll
        for (int r = 0; r < 4; ++r) ov[r] = (bf16)(Oacc[g][ni][r] * rn);
        *(bf16x4*)&X[((size_t)(b * NN) + q0 + g * 16 + l15) * CC
                     + h * HD + ni * 16 + quad * 4] = ov;
      }
    }
  }
}

// ---------------- projection GEMM: 64x128 tile, BK=64, 8-slot swizzle, grid 512
__global__ __launch_bounds__(256, 4)
void gemm_proj(const bf16* __restrict__ A, const bf16* __restrict__ Bt,
               float* __restrict__ Out) {
  __shared__ bf16 As[64 * 64];
  __shared__ bf16 Bs[128 * 64];
  const int bid = blockIdx.x;
  const int u = bid & 7, s = bid >> 3;        // s in [0,64)
  const int m0 = (u * 8 + (s >> 3)) * 64;
  const int n0 = (s & 7) * 128;
  const int tid = threadIdx.x;
  const int wave = tid >> 6, lane = tid & 63;
  const int quad = lane >> 4, l15 = lane & 15;
  const int waveM = (wave >> 1) * 32, waveN = (wave & 1) * 64;
  f32x4 acc[2][4] = {};

  for (int k0 = 0; k0 < CC; k0 += 64) {
#pragma unroll
    for (int p = 0; p < 2; ++p) {
      int ch = p * 256 + tid;
      int r = ch >> 3, c = (ch & 7) ^ (r & 7);
      gload_lds16(A + (size_t)(m0 + r) * CC + k0 + c * 8, &As[ch * 8]);
    }
#pragma unroll
    for (int p = 0; p < 4; ++p) {
      int ch = p * 256 + tid;
      int r = ch >> 3, c = (ch & 7) ^ (r & 7);
      gload_lds16(Bt + (size_t)(n0 + r) * CC + k0 + c * 8, &Bs[ch * 8]);
    }
    __syncthreads();
    bf16x8 af[2][2], bfr[4][2];
#pragma unroll
    for (int i = 0; i < 2; ++i) {
      int rA = waveM + i * 16 + l15;
      af[i][0] = *(const bf16x8*)&As[(rA * 8 + (quad ^ (rA & 7))) * 8];
      af[i][1] = *(const bf16x8*)&As[(rA * 8 + ((quad + 4) ^ (rA & 7))) * 8];
    }
#pragma unroll
    for (int i = 0; i < 4; ++i) {
      int rB = waveN + i * 16 + l15;
      bfr[i][0] = *(const bf16x8*)&Bs[(rB * 8 + (quad ^ (rB & 7))) * 8];
      bfr[i][1] = *(const bf16x8*)&Bs[(rB * 8 + ((quad + 4) ^ (rB & 7))) * 8];
    }
#pragma unroll
    for (int mi = 0; mi < 2; ++mi)
#pragma unroll
      for (int ni = 0; ni < 4; ++ni) {
        acc[mi][ni] = __builtin_amdgcn_mfma_f32_16x16x32_bf16(
            af[mi][0], bfr[ni][0], acc[mi][ni], 0, 0, 0);
        acc[mi][ni] = __builtin_amdgcn_mfma_f32_16x16x32_bf16(
            af[mi][1], bfr[ni][1], acc[mi][ni], 0, 0, 0);
      }
    __syncthreads();
  }
#pragma unroll
  for (int mi = 0; mi < 2; ++mi)
#pragma unroll
    for (int ni = 0; ni < 4; ++ni)
#pragma unroll
      for (int r = 0; r < 4; ++r) {
        int row = m0 + waveM + mi * 16 + quad * 4 + r;
        int col = n0 + waveN + ni * 16 + l15;
        Out[(size_t)row * CC + col] = acc[mi][ni][r];
      }
}

extern "C" void kernel_launch(void* const* d_in, const int* in_sizes, int n_in,
                              void* d_out, int out_size, void* d_ws, size_t ws_size,
                              hipStream_t stream) {
  const float* q    = (const float*)d_in[0];
  const float* k    = (const float*)d_in[1];
  const float* v    = (const float*)d_in[2];
  const int*   mask = (const int*)d_in[3];
  const float* pos  = (const float*)d_in[4];
  const float* qW   = (const float*)d_in[5];
  const float* kW   = (const float*)d_in[6];
  const float* vW   = (const float*)d_in[7];
  const float* pW   = (const float*)d_in[8];
  float* out = (float*)d_out;

  char* w = (char*)d_ws;
  const size_t MB = 1024 * 1024;
  // ws <= 44 MB (round-7 proven layout):
  //  wtrans:    W Wt[0,8)
  //  gemm_qkv:  R d_in,Wt       W Qp[8,16) Kp[16,24) Vp[24,32)
  //  kpack:     R Kp[16,24)     W Kpack[32,40)
  //  vpack:     R Vp[24,32)     W VpA[0,6) (dead qWt/kWt/vWt; pWt[6,8) kept), VpB[40,44)
  //  attn3:     R Qp,Kpack,VpA,VpB   W X[16,24) (dead Kp)
  //  gemm_proj: R X,pWt[6,8)    W d_out
  bf16* Wt    = (bf16*)(w);
  bf16* Qp    = (bf16*)(w + 8 * MB);
  bf16* Kp    = (bf16*)(w + 16 * MB);
  bf16* Vp    = (bf16*)(w + 24 * MB);
  bf16* Kpack = (bf16*)(w + 32 * MB);
  bf16* VpA   = (bf16*)(w);
  bf16* VpB   = (bf16*)(w + 40 * MB);
  bf16* X     = (bf16*)(w + 16 * MB);

  wtrans<<<dim3(16, 16, 4), 256, 0, stream>>>(qW, kW, vW, pW, Wt);
  gemm_qkv<<<dim3(768), 256, 0, stream>>>(q, k, v, Wt, pos, Qp, Kp, Vp);
  kpack_kernel<<<dim3(KVN / 64, HH, BB), 256, 0, stream>>>(Kp, Kpack);
  vpack_kernel<<<dim3(KVN / 64, HH, BB), 256, 0, stream>>>(Vp, mask, VpA, VpB);
  attn3<<<dim3(512), 256, 0, stream>>>(Qp, Kpack, VpA, VpB, X);
  gemm_proj<<<dim3(512), 256, 0, stream>>>(X, Wt + 3 * (size_t)CC * CC, out);
}